// Round 1
// baseline (1177.036 us; speedup 1.0000x reference)
//
#include <hip/hip_runtime.h>
#include <stdint.h>

#define ROWS 4096
#define DIM 1024
#define VOCAB 32000
#define BM 128
#define BN 128
#define NTILES (VOCAB / BN)  // 250
#define NCHUNKS 16           // 32 row-blocks * 16 = 512 blocks = 2/CU, all co-resident
#define SCALE 2048.0f        // keeps f16 lo-plane normal; argmax is scale-invariant

typedef float floatx4 __attribute__((ext_vector_type(4)));
typedef _Float16 f16x8 __attribute__((ext_vector_type(8)));
typedef _Float16 f16x4 __attribute__((ext_vector_type(4)));

__device__ __forceinline__ void load_lds16(const _Float16* g, _Float16* l) {
    __builtin_amdgcn_global_load_lds(
        (const __attribute__((address_space(1))) uint32_t*)g,
        (__attribute__((address_space(3))) uint32_t*)l, 16, 0, 0);
}

// ---- kernel 0 (fallback path only): zero the per-row argmax keys ----
__global__ void init_keys(unsigned long long* __restrict__ keys) {
    int i = blockIdx.x * 256 + threadIdx.x;
    if (i < ROWS) keys[i] = 0ull;
}

// ---- fused prep: keys init + A=emb+noise split + B=table split (f16 hi/lo planes) ----
__global__ void prep(const float* __restrict__ emb, const float* __restrict__ noi,
                     const float* __restrict__ table,
                     _Float16* __restrict__ Ah, _Float16* __restrict__ Al,
                     _Float16* __restrict__ Bh, _Float16* __restrict__ Bl,
                     unsigned long long* __restrict__ keys) {
    const int bid = blockIdx.x;
    const int ABLK = ROWS * DIM / 8 / 256;  // 2048
    if (bid < ABLK) {
        if (bid < ROWS / 256) keys[bid * 256 + threadIdx.x] = 0ull;
        size_t i = ((size_t)bid * 256 + threadIdx.x) * 8;
        floatx4 a = *(const floatx4*)(emb + i);
        floatx4 b = *(const floatx4*)(emb + i + 4);
        floatx4 c = *(const floatx4*)(noi + i);
        floatx4 d = *(const floatx4*)(noi + i + 4);
        f16x8 h, l;
#pragma unroll
        for (int j = 0; j < 4; j++) {
            float p = (a[j] + c[j]) * SCALE;
            _Float16 hh = (_Float16)p;
            h[j] = hh; l[j] = (_Float16)(p - (float)hh);
            float q = (b[j] + d[j]) * SCALE;
            _Float16 hq = (_Float16)q;
            h[4 + j] = hq; l[4 + j] = (_Float16)(q - (float)hq);
        }
        *(f16x8*)(Ah + i) = h;
        *(f16x8*)(Al + i) = l;
    } else {
        size_t i = ((size_t)(bid - ABLK) * 256 + threadIdx.x) * 8;
        floatx4 a = *(const floatx4*)(table + i);
        floatx4 b = *(const floatx4*)(table + i + 4);
        f16x8 h, l;
#pragma unroll
        for (int j = 0; j < 4; j++) {
            float p = a[j] * SCALE;
            _Float16 hh = (_Float16)p;
            h[j] = hh; l[j] = (_Float16)(p - (float)hh);
            float q = b[j] * SCALE;
            _Float16 hq = (_Float16)q;
            h[4 + j] = hq; l[4 + j] = (_Float16)(q - (float)hq);
        }
        *(f16x8*)(Bh + i) = h;
        *(f16x8*)(Bl + i) = l;
    }
}

// ---- main GEMM+argmax: double-buffered LDS, counted vmcnt prefetch, ----
// ---- conflict-free piece-major LDS layout.                          ----
// grid = 32 * NCHUNKS = 512; block = 256 (4 waves, 2x2 wave grid). BK=32.
//
// LDS plane layout: 8 blocks of (16 rows x 32 f16) stored piece-major:
//   elem_off(block, row, piece) = block*512 + piece*128 + row*8
// global_load_lds writes lane l at +l*16B, so lane l fetches
//   row = blk*16 + (l&15), k-piece = (l>>4)   (per-lane global src is free).
// Fragment read for lane(quad,lq) is then base + lane*16B: a contiguous 1 KB
// ds_read_b128 per wave -> zero bank conflicts by construction.
__global__ __launch_bounds__(256, 2) void gemm_argmax_pre(
    const _Float16* __restrict__ Ah, const _Float16* __restrict__ Al,
    const _Float16* __restrict__ Bh, const _Float16* __restrict__ Bl,
    unsigned long long* __restrict__ keys) {
    __shared__ __align__(16) _Float16 sAh[2][BM * 32];
    __shared__ __align__(16) _Float16 sAl[2][BM * 32];
    __shared__ __align__(16) _Float16 sBh[2][BN * 32];
    __shared__ __align__(16) _Float16 sBl[2][BN * 32];
    __shared__ unsigned long long redk[BM];

    const int tid = threadIdx.x;
    const int w = tid >> 6, lane = tid & 63;
    const int quad = lane >> 4, lq = lane & 15;
    const int rb = blockIdx.x / NCHUNKS, chunk = blockIdx.x % NCHUNKS;
    const int row0 = rb * BM;
    const int wmb = (w & 1) * 4, wnb = (w >> 1) * 4;  // 16-row block indices
    const int wm = wmb * 16, wn = wnb * 16;
    const int tstart = chunk * NTILES / NCHUNKS;
    const int tend = (chunk + 1) * NTILES / NCHUNKS;

    if (tid < BM) redk[tid] = 0ull;  // barriers intervene before use

    // runtime layout probe: c1 slot value = logical m, c2 = logical n
    union PF { f16x8 v; _Float16 s[8]; } fidx, fone;
#pragma unroll
    for (int j = 0; j < 8; j++) { fidx.s[j] = (_Float16)0.0f; fone.s[j] = (_Float16)0.0f; }
    if (quad == 0) { fidx.s[0] = (_Float16)(float)lq; fone.s[0] = (_Float16)1.0f; }
    floatx4 c1 = {0.f, 0.f, 0.f, 0.f}, c2 = {0.f, 0.f, 0.f, 0.f};
    c1 = __builtin_amdgcn_mfma_f32_16x16x32_f16(fidx.v, fone.v, c1, 0, 0, 0);
    c2 = __builtin_amdgcn_mfma_f32_16x16x32_f16(fone.v, fidx.v, c2, 0, 0, 0);
    int m_of[4], n_of[4];
#pragma unroll
    for (int r = 0; r < 4; r++) {
        m_of[r] = (int)(c1[r] + 0.5f);
        n_of[r] = (int)(c2[r] + 0.5f);
    }

    // wave -> plane assignment for staging (wave-uniform)
    const _Float16* gbase = (w == 0) ? (Ah + (size_t)row0 * DIM)
                        : (w == 1) ? (Al + (size_t)row0 * DIM)
                        : (w == 2) ? Bh : Bl;  // B base gets +n0*DIM per tile
    _Float16* lbase = (w == 0) ? sAh[0] : (w == 1) ? sAl[0] : (w == 2) ? sBh[0] : sBl[0];
    const size_t g_lane = (size_t)(lane & 15) * DIM + (size_t)(lane >> 4) * 8;
    const int loff = quad * 128 + lq * 8;  // piece-major intra-block offset
    const bool isB = (w >= 2);

    float rmax[16];
    int ridx[16];
#pragma unroll
    for (int i = 0; i < 16; i++) { rmax[i] = -3.4e38f; ridx[i] = 0; }

    // stage one plane's (16-row x 32-f16) x 8 blocks for K-step kt of tile t
#define STAGE(buf, t, kt)                                                        \
    do {                                                                         \
        const _Float16* gs_ = gbase + (isB ? (size_t)(t) * BN * DIM : 0)         \
                              + (kt) * 32 + g_lane;                              \
        _Float16* ld_ = lbase + (buf) * (BM * 32);                               \
        _Pragma("unroll")                                                        \
        for (int c_ = 0; c_ < 8; c_++)                                           \
            load_lds16(gs_ + (size_t)(c_ * 16) * DIM, ld_ + c_ * 512);           \
    } while (0)

    int cur = 0;
    STAGE(0, tstart, 0);  // prologue prefetch (8 loads in flight)

    for (int t = tstart; t < tend; ++t) {
        const int n0 = t * BN;
        floatx4 acc[4][4];
#pragma unroll
        for (int mi = 0; mi < 4; mi++)
#pragma unroll
            for (int ni = 0; ni < 4; ni++)
#pragma unroll
                for (int r = 0; r < 4; r++) acc[mi][ni][r] = 0.0f;

        for (int kt = 0; kt < DIM / 32; ++kt) {
            // issue next step's staging first; it targets buf[cur^1], whose
            // readers all finished before the end-barrier of the previous step.
            int nt_ = t, nk = kt + 1;
            if (nk == DIM / 32) { nk = 0; ++nt_; }
            if (nt_ < tend) {
                STAGE(cur ^ 1, nt_, nk);
                // wait only for the 8 older loads (buf[cur]); keep 8 in flight
                asm volatile("s_waitcnt vmcnt(8)" ::: "memory");
            } else {
                asm volatile("s_waitcnt vmcnt(0)" ::: "memory");
            }
            __builtin_amdgcn_s_barrier();  // all waves' buf[cur] loads landed

            __builtin_amdgcn_s_setprio(1);
            f16x8 ahf[4], alf[4];
#pragma unroll
            for (int i = 0; i < 4; i++) {
                ahf[i] = *(const f16x8*)(&sAh[cur][(wmb + i) * 512 + loff]);
                alf[i] = *(const f16x8*)(&sAl[cur][(wmb + i) * 512 + loff]);
            }
#pragma unroll
            for (int ni = 0; ni < 4; ni++) {
                f16x8 bh = *(const f16x8*)(&sBh[cur][(wnb + ni) * 512 + loff]);
                f16x8 bl = *(const f16x8*)(&sBl[cur][(wnb + ni) * 512 + loff]);
#pragma unroll
                for (int mi = 0; mi < 4; mi++) {
                    acc[mi][ni] = __builtin_amdgcn_mfma_f32_16x16x32_f16(
                        ahf[mi], bh, acc[mi][ni], 0, 0, 0);
                    acc[mi][ni] = __builtin_amdgcn_mfma_f32_16x16x32_f16(
                        ahf[mi], bl, acc[mi][ni], 0, 0, 0);
                    acc[mi][ni] = __builtin_amdgcn_mfma_f32_16x16x32_f16(
                        alf[mi], bh, acc[mi][ni], 0, 0, 0);
                }
            }
            __builtin_amdgcn_s_setprio(0);

            // all my LDS reads complete before signaling; the barrier then
            // licenses every wave to overwrite buf[cur] next step.
            asm volatile("s_waitcnt lgkmcnt(0)" ::: "memory");
            __builtin_amdgcn_s_barrier();
            cur ^= 1;
        }
        // fold this n-tile into per-row running argmax (probed layout)
#pragma unroll
        for (int mi = 0; mi < 4; mi++)
#pragma unroll
            for (int ni = 0; ni < 4; ni++)
#pragma unroll
                for (int r = 0; r < 4; r++) {
                    float v = acc[mi][ni][r];
                    int col = n0 + wn + ni * 16 + n_of[r];
                    int s = mi * 4 + r;
                    if (v > rmax[s] || (v == rmax[s] && col < ridx[s])) {
                        rmax[s] = v;
                        ridx[s] = col;
                    }
                }
    }
#undef STAGE

    // reduce: LDS atomicMax keyed by probed row, then one global atomic per row
#pragma unroll
    for (int s = 0; s < 16; ++s) {
        int mi = s >> 2, r = s & 3;
        int rowl = wm + mi * 16 + m_of[r];
        union { float f; uint32_t i; } u;
        u.f = rmax[s];
        uint32_t ord = (u.i & 0x80000000u) ? ~u.i : (u.i | 0x80000000u);
        unsigned long long key =
            ((unsigned long long)ord << 32) | (uint32_t)(~(uint32_t)ridx[s]);
        atomicMax(&redk[rowl], key);
    }
    __syncthreads();
    if (tid < BM) atomicMax(&keys[row0 + tid], redk[tid]);
}

// ================== fallback path (verified): in-kernel split ==================
#define BKF 64
#define LDKF 72
#define TILES_PER_WGF 10
#define NCHUNKSF 25

__global__ __launch_bounds__(256, 2) void gemm_argmax_fused(
    const float* __restrict__ emb, const float* __restrict__ noi,
    const float* __restrict__ table, unsigned long long* __restrict__ keys) {
    __shared__ __align__(16) _Float16 Ah[BM * LDKF];
    __shared__ __align__(16) _Float16 Al[BM * LDKF];
    __shared__ __align__(16) _Float16 Bh[BN * LDKF];
    __shared__ __align__(16) _Float16 Bl[BN * LDKF];
    __shared__ unsigned long long redk[BM];

    const int tid = threadIdx.x;
    const int wave = tid >> 6, lane = tid & 63;
    const int quad = lane >> 4, lq = lane & 15;
    const int rb = blockIdx.x / NCHUNKSF, chunk = blockIdx.x % NCHUNKSF;
    const int row0 = rb * BM;
    const int wm = (wave & 1) * 64, wn = (wave >> 1) * 64;

    if (tid < BM) redk[tid] = 0ull;

    union PF { f16x8 v; _Float16 s[8]; } fidx, fone;
#pragma unroll
    for (int j = 0; j < 8; j++) { fidx.s[j] = (_Float16)0.0f; fone.s[j] = (_Float16)0.0f; }
    if (quad == 0) { fidx.s[0] = (_Float16)(float)lq; fone.s[0] = (_Float16)1.0f; }
    floatx4 c1 = {0.f, 0.f, 0.f, 0.f}, c2 = {0.f, 0.f, 0.f, 0.f};
    c1 = __builtin_amdgcn_mfma_f32_16x16x32_f16(fidx.v, fone.v, c1, 0, 0, 0);
    c2 = __builtin_amdgcn_mfma_f32_16x16x32_f16(fone.v, fidx.v, c2, 0, 0, 0);
    int m_of[4], n_of[4];
#pragma unroll
    for (int r = 0; r < 4; r++) {
        m_of[r] = (int)(c1[r] + 0.5f);
        n_of[r] = (int)(c2[r] + 0.5f);
    }

    float rmax[16];
    int ridx[16];
#pragma unroll
    for (int i = 0; i < 16; i++) { rmax[i] = -3.4e38f; ridx[i] = 0; }

    for (int t = 0; t < TILES_PER_WGF; ++t) {
        const int n0 = (chunk * TILES_PER_WGF + t) * BN;
        floatx4 acc[4][4];
#pragma unroll
        for (int mi = 0; mi < 4; mi++)
#pragma unroll
            for (int ni = 0; ni < 4; ni++)
#pragma unroll
                for (int r = 0; r < 4; r++) acc[mi][ni][r] = 0.0f;

        for (int kt = 0; kt < DIM / BKF; ++kt) {
            const int k0 = kt * BKF;
            __syncthreads();
#pragma unroll
            for (int i = 0; i < 8; i++) {
                int c = i * 256 + tid;
                int r = c >> 4, q = c & 15;
                floatx4 e = *(const floatx4*)(emb + (size_t)(row0 + r) * DIM + k0 + q * 4);
                floatx4 n = *(const floatx4*)(noi + (size_t)(row0 + r) * DIM + k0 + q * 4);
                floatx4 b = *(const floatx4*)(table + (size_t)(n0 + r) * DIM + k0 + q * 4);
                f16x4 ah, al, bh, bl;
#pragma unroll
                for (int j = 0; j < 4; j++) {
                    float pa = (e[j] + n[j]) * SCALE;
                    _Float16 h = (_Float16)pa;
                    ah[j] = h;
                    al[j] = (_Float16)(pa - (float)h);
                    float pb = b[j] * SCALE;
                    _Float16 hb = (_Float16)pb;
                    bh[j] = hb;
                    bl[j] = (_Float16)(pb - (float)hb);
                }
                *(f16x4*)(Ah + r * LDKF + q * 4) = ah;
                *(f16x4*)(Al + r * LDKF + q * 4) = al;
                *(f16x4*)(Bh + r * LDKF + q * 4) = bh;
                *(f16x4*)(Bl + r * LDKF + q * 4) = bl;
            }
            __syncthreads();
#pragma unroll
            for (int ks = 0; ks < BKF; ks += 32) {
                f16x8 bhf[4], blf[4], ahf[4], alf[4];
#pragma unroll
                for (int i = 0; i < 4; i++) {
                    bhf[i] = *(const f16x8*)(Bh + (wn + i * 16 + lq) * LDKF + ks + quad * 8);
                    blf[i] = *(const f16x8*)(Bl + (wn + i * 16 + lq) * LDKF + ks + quad * 8);
                    ahf[i] = *(const f16x8*)(Ah + (wm + i * 16 + lq) * LDKF + ks + quad * 8);
                    alf[i] = *(const f16x8*)(Al + (wm + i * 16 + lq) * LDKF + ks + quad * 8);
                }
#pragma unroll
                for (int mi = 0; mi < 4; mi++)
#pragma unroll
                    for (int ni = 0; ni < 4; ni++) {
                        acc[mi][ni] = __builtin_amdgcn_mfma_f32_16x16x32_f16(
                            ahf[mi], bhf[ni], acc[mi][ni], 0, 0, 0);
                        acc[mi][ni] = __builtin_amdgcn_mfma_f32_16x16x32_f16(
                            ahf[mi], blf[ni], acc[mi][ni], 0, 0, 0);
                        acc[mi][ni] = __builtin_amdgcn_mfma_f32_16x16x32_f16(
                            alf[mi], bhf[ni], acc[mi][ni], 0, 0, 0);
                    }
            }
        }
#pragma unroll
        for (int mi = 0; mi < 4; mi++)
#pragma unroll
            for (int ni = 0; ni < 4; ni++)
#pragma unroll
                for (int r = 0; r < 4; r++) {
                    float v = acc[mi][ni][r];
                    int col = n0 + wn + ni * 16 + n_of[r];
                    int s = mi * 4 + r;
                    if (v > rmax[s] || (v == rmax[s] && col < ridx[s])) {
                        rmax[s] = v;
                        ridx[s] = col;
                    }
                }
    }

#pragma unroll
    for (int s = 0; s < 16; ++s) {
        int mi = s >> 2, r = s & 3;
        int rowl = wm + mi * 16 + m_of[r];
        union { float f; uint32_t i; } u;
        u.f = rmax[s];
        uint32_t ord = (u.i & 0x80000000u) ? ~u.i : (u.i | 0x80000000u);
        unsigned long long key =
            ((unsigned long long)ord << 32) | (uint32_t)(~(uint32_t)ridx[s]);
        atomicMax(&redk[rowl], key);
    }
    __syncthreads();
    if (tid < BM) atomicMax(&keys[row0 + tid], redk[tid]);
}

// ---- gather winning table rows (f32) to output ----
__global__ void gather_kernel(const unsigned long long* __restrict__ keys,
                              const float* __restrict__ table,
                              float* __restrict__ out) {
    int row = blockIdx.x;
    unsigned long long key = keys[row];
    uint32_t ix = ~(uint32_t)(key & 0xFFFFFFFFull);
    const floatx4* src = (const floatx4*)(table + (size_t)ix * DIM);
    floatx4* dst = (floatx4*)(out + (size_t)row * DIM);
    dst[threadIdx.x] = src[threadIdx.x];  // 256 * 16B = 4 KB row
}

extern "C" void kernel_launch(void* const* d_in, const int* in_sizes, int n_in,
                              void* d_out, int out_size, void* d_ws, size_t ws_size,
                              hipStream_t stream) {
    (void)in_sizes; (void)n_in; (void)out_size;
    const float* emb = (const float*)d_in[0];
    const float* table = (const float*)d_in[1];
    const float* noi = (const float*)d_in[2];
    float* out = (float*)d_out;

    uint8_t* ws = (uint8_t*)d_ws;
    unsigned long long* keys = (unsigned long long*)ws;
    const size_t keysB = (size_t)ROWS * 8;
    const size_t aB = (size_t)ROWS * DIM * 2;    // 8.39 MB per A plane
    const size_t bB = (size_t)VOCAB * DIM * 2;   // 65.5 MB per B plane
    const size_t need = keysB + 2 * aB + 2 * bB; // ~141 MB

    if (ws_size >= need) {
        _Float16* Ah = (_Float16*)(ws + keysB);
        _Float16* Al = (_Float16*)(ws + keysB + aB);
        _Float16* Bh = (_Float16*)(ws + keysB + 2 * aB);
        _Float16* Bl = (_Float16*)(ws + keysB + 2 * aB + bB);
        const int ablk = ROWS * DIM / 8 / 256;       // 2048
        const int bblk = VOCAB * DIM / 8 / 256;      // 16000
        prep<<<ablk + bblk, 256, 0, stream>>>(emb, noi, table, Ah, Al, Bh, Bl, keys);
        gemm_argmax_pre<<<(ROWS / BM) * NCHUNKS, 256, 0, stream>>>(Ah, Al, Bh, Bl, keys);
    } else {
        init_keys<<<ROWS / 256, 256, 0, stream>>>(keys);
        gemm_argmax_fused<<<(ROWS / BM) * NCHUNKSF, 256, 0, stream>>>(emb, noi, table, keys);
    }
    gather_kernel<<<ROWS, 256, 0, stream>>>(keys, table, out);
}